// Round 1
// baseline (1792.332 us; speedup 1.0000x reference)
//
#include <hip/hip_runtime.h>
#include <math.h>

#define NG 110592          // 48*48*48
#define NCH 128            // conv channels
#define NKP 512
#define EPSN 1e-5f

// ---------------- W transpose: [co][ci*27+k] -> [ci*27+k][co] ----------------
__global__ __launch_bounds__(256) void k_transpose_w(const float* __restrict__ W0,
                                                     float* __restrict__ Wt) {
    int idx = blockIdx.x * 256 + threadIdx.x;     // 128*3456 = 442368 exact
    int co = idx / 3456;
    int r  = idx % 3456;                           // ci*27 + k
    Wt[r * 128 + co] = W0[idx];
}

// ---------------- conv3d + bias + relu + instance-norm stats ----------------
// block: tile 4z x 4y x 8x voxels (128) x 128 co, 256 threads,
// micro-tile 8 vox (x-row) x 8 co per thread.
__global__ __launch_bounds__(256) void k_conv(const float* __restrict__ feats,
                                              const float* __restrict__ Wt,
                                              const float* __restrict__ b0,
                                              float* __restrict__ yout,
                                              float* __restrict__ gsum,
                                              float* __restrict__ gsq) {
    __shared__ __align__(16) float  xs[432];      // 6z * 6y * 12x (x padded 10->12)
    __shared__ float4 ws4[864];                   // 27k * 128co floats
    __shared__ float  lsum[128], lsq[128];

    const int tid = threadIdx.x;
    const int blk = blockIdx.x;                   // 864 blocks: 12z * 12y * 6x
    const int bz = blk / 72, by = (blk % 72) / 6, bx = blk % 6;
    const int z0 = bz * 4, y0v = by * 4, x0 = bx * 8;

    const int tg = tid >> 4;                      // 0..15 -> (vz,vy)
    const int tx = tid & 15;                      // co group
    const int vz = tg >> 2, vy = tg & 3;
    const int co0 = tx * 8;

    float acc[8][8];
    #pragma unroll
    for (int a = 0; a < 8; ++a)
        #pragma unroll
        for (int b = 0; b < 8; ++b) acc[a][b] = 0.f;

    if (tid < 128) { lsum[tid] = 0.f; lsq[tid] = 0.f; }

    const float sc = 2.0f / 47.0f;

    for (int ci = 0; ci < 128; ++ci) {
        // stage input halo tile for this ci (zero-padded, grid channels computed)
        for (int s = tid; s < 432; s += 256) {
            int xi = s % 12, yi = (s / 12) % 6, zi = s / 72;
            int gx = x0 - 1 + xi, gy = y0v - 1 + yi, gz = z0 - 1 + zi;
            float v = 0.f;
            if (xi < 10 && gx >= 0 && gx < 48 && gy >= 0 && gy < 48 && gz >= 0 && gz < 48) {
                if (ci < 125) {
                    v = feats[(size_t)ci * NG + gz * 2304 + gy * 48 + gx];
                } else {
                    int cc = ci - 125;
                    int coord = (cc == 0) ? gx : ((cc == 1) ? gy : gz);
                    v = coord * sc - 1.0f;
                }
            }
            xs[s] = v;
        }
        // stage W slice [27][128] for this ci
        const float4* Wt4 = (const float4*)(Wt + (size_t)ci * 3456);
        for (int s = tid; s < 864; s += 256) ws4[s] = Wt4[s];
        __syncthreads();

        #pragma unroll
        for (int dz = 0; dz < 3; ++dz)
        #pragma unroll
        for (int dy = 0; dy < 3; ++dy) {
            const float* row = &xs[((vz + dz) * 6 + (vy + dy)) * 12];
            float4 A = *(const float4*)row;
            float4 B = *(const float4*)(row + 4);
            float2 Cc = *(const float2*)(row + 8);
            float r[10] = {A.x, A.y, A.z, A.w, B.x, B.y, B.z, B.w, Cc.x, Cc.y};
            #pragma unroll
            for (int dx = 0; dx < 3; ++dx) {
                int k = (dz * 3 + dy) * 3 + dx;
                float4 w0 = ws4[k * 32 + tx * 2];
                float4 w1 = ws4[k * 32 + tx * 2 + 1];
                float wv[8] = {w0.x, w0.y, w0.z, w0.w, w1.x, w1.y, w1.z, w1.w};
                #pragma unroll
                for (int j = 0; j < 8; ++j)
                    #pragma unroll
                    for (int vx = 0; vx < 8; ++vx)
                        acc[vx][j] = fmaf(r[vx + dx], wv[j], acc[vx][j]);
            }
        }
        __syncthreads();
    }

    // epilogue: bias + relu + store + stats
    const int zz = z0 + vz, yy = y0v + vy;
    #pragma unroll
    for (int j = 0; j < 8; ++j) {
        float b = b0[co0 + j];
        float s = 0.f, q = 0.f;
        #pragma unroll
        for (int vx = 0; vx < 8; ++vx) {
            float v = acc[vx][j] + b;
            v = v > 0.f ? v : 0.f;
            yout[(size_t)(co0 + j) * NG + zz * 2304 + yy * 48 + x0 + vx] = v;
            s += v; q += v * v;
        }
        atomicAdd(&lsum[co0 + j], s);
        atomicAdd(&lsq[co0 + j], q);
    }
    __syncthreads();
    if (tid < 128) {
        atomicAdd(&gsum[tid], lsum[tid]);
        atomicAdd(&gsq[tid], lsq[tid]);
    }
}

// ---------------- finalize instance-norm params ----------------
__global__ void k_finalize(const float* __restrict__ gsum, const float* __restrict__ gsq,
                           float* __restrict__ mu, float* __restrict__ inv) {
    int c = threadIdx.x;
    float m = gsum[c] * (1.0f / NG);
    float v = gsq[c] * (1.0f / NG) - m * m;
    mu[c] = m;
    inv[c] = rsqrtf(v + EPSN);
}

// ---------------- sample fk at keypoints (normalized), and ||fk||^2 ----------------
__global__ __launch_bounds__(128) void k_sample(const float* __restrict__ kpts,
                                                const float* __restrict__ yin,
                                                const float* __restrict__ mu,
                                                const float* __restrict__ inv,
                                                float* __restrict__ fkT,
                                                float* __restrict__ fkn2) {
    __shared__ float red[128];
    const int n = blockIdx.x, c = threadIdx.x;
    float px = kpts[n * 3 + 0], py = kpts[n * 3 + 1], pz = kpts[n * 3 + 2];
    float ix = (px + 1.f) * 0.5f * 47.f;
    float iy = (py + 1.f) * 0.5f * 47.f;
    float iz = (pz + 1.f) * 0.5f * 47.f;
    float xf = floorf(ix), yf = floorf(iy), zf = floorf(iz);
    float wx = ix - xf, wy = iy - yf, wz = iz - zf;
    int x0 = min(max((int)xf, 0), 47), y0 = min(max((int)yf, 0), 47), z0 = min(max((int)zf, 0), 47);
    int x1 = min(x0 + 1, 47), y1 = min(y0 + 1, 47), z1 = min(z0 + 1, 47);

    const float* base = yin + (size_t)c * NG;
    float v000 = base[z0 * 2304 + y0 * 48 + x0];
    float v001 = base[z0 * 2304 + y0 * 48 + x1];
    float v010 = base[z0 * 2304 + y1 * 48 + x0];
    float v011 = base[z0 * 2304 + y1 * 48 + x1];
    float v100 = base[z1 * 2304 + y0 * 48 + x0];
    float v101 = base[z1 * 2304 + y0 * 48 + x1];
    float v110 = base[z1 * 2304 + y1 * 48 + x0];
    float v111 = base[z1 * 2304 + y1 * 48 + x1];

    float val = v000 * (1 - wz) * (1 - wy) * (1 - wx)
              + v001 * (1 - wz) * (1 - wy) * wx
              + v010 * (1 - wz) * wy * (1 - wx)
              + v011 * (1 - wz) * wy * wx
              + v100 * wz * (1 - wy) * (1 - wx)
              + v101 * wz * (1 - wy) * wx
              + v110 * wz * wy * (1 - wx)
              + v111 * wz * wy * wx;

    val = (val - mu[c]) * inv[c];
    fkT[c * NKP + n] = val;                      // [c][n] layout
    red[c] = val * val;
    __syncthreads();
    for (int s = 64; s > 0; s >>= 1) {
        if (c < s) red[c] += red[c + s];
        __syncthreads();
    }
    if (c == 0) fkn2[n] = red[0];
}

// ---------------- flash-style softmax over keypoints + disp reduce ----------------
// block: 64 voxels, 256 threads (16 vox-groups x 16 n-groups), 8 chunks of 64 keys.
__global__ __launch_bounds__(256) void k_attn(const float* __restrict__ yin,
                                              const float* __restrict__ mu,
                                              const float* __restrict__ inv,
                                              const float* __restrict__ fkT,
                                              const float* __restrict__ fkn2,
                                              const float* __restrict__ disp,
                                              float* __restrict__ out) {
    __shared__ __align__(16) float4 fgs[128 * 16];   // [c][64v] normalized fg tile
    __shared__ __align__(16) float4 fks[128 * 16];   // [c][64n] fk chunk
    __shared__ float fk2s[64];
    __shared__ float dsp[1536];

    const int tid = threadIdx.x;
    const int gbase = blockIdx.x * 64;
    const int tv = tid >> 4, tn = tid & 15;

    for (int s = tid; s < 2048; s += 256) {
        int c = s >> 4, v4 = s & 15;
        float4 t = *(const float4*)(yin + (size_t)c * NG + gbase + v4 * 4);
        float m = mu[c], iv = inv[c];
        t.x = (t.x - m) * iv; t.y = (t.y - m) * iv;
        t.z = (t.z - m) * iv; t.w = (t.w - m) * iv;
        fgs[s] = t;
    }
    for (int s = tid; s < 1536; s += 256) dsp[s] = disp[s];

    float mrun[4], lrun[4], orun[4][3];
    #pragma unroll
    for (int i = 0; i < 4; ++i) {
        mrun[i] = -1e30f; lrun[i] = 0.f;
        orun[i][0] = 0.f; orun[i][1] = 0.f; orun[i][2] = 0.f;
    }
    __syncthreads();

    for (int ch = 0; ch < 8; ++ch) {
        for (int s = tid; s < 2048; s += 256) {
            int c = s >> 4, j4 = s & 15;
            fks[s] = *(const float4*)(fkT + c * NKP + ch * 64 + j4 * 4);
        }
        if (tid < 64) fk2s[tid] = fkn2[ch * 64 + tid];
        __syncthreads();

        float S[4][4];
        #pragma unroll
        for (int i = 0; i < 4; ++i)
            #pragma unroll
            for (int j = 0; j < 4; ++j) S[i][j] = 0.f;

        for (int c = 0; c < 128; ++c) {
            float4 a = fgs[c * 16 + tv];
            float4 b = fks[c * 16 + tn];
            S[0][0] = fmaf(a.x, b.x, S[0][0]); S[0][1] = fmaf(a.x, b.y, S[0][1]);
            S[0][2] = fmaf(a.x, b.z, S[0][2]); S[0][3] = fmaf(a.x, b.w, S[0][3]);
            S[1][0] = fmaf(a.y, b.x, S[1][0]); S[1][1] = fmaf(a.y, b.y, S[1][1]);
            S[1][2] = fmaf(a.y, b.z, S[1][2]); S[1][3] = fmaf(a.y, b.w, S[1][3]);
            S[2][0] = fmaf(a.z, b.x, S[2][0]); S[2][1] = fmaf(a.z, b.y, S[2][1]);
            S[2][2] = fmaf(a.z, b.z, S[2][2]); S[2][3] = fmaf(a.z, b.w, S[2][3]);
            S[3][0] = fmaf(a.w, b.x, S[3][0]); S[3][1] = fmaf(a.w, b.y, S[3][1]);
            S[3][2] = fmaf(a.w, b.z, S[3][2]); S[3][3] = fmaf(a.w, b.w, S[3][3]);
        }

        // logits = 2*cross - ||fk||^2  (row-constant ||fg||^2 dropped)
        #pragma unroll
        for (int i = 0; i < 4; ++i)
            #pragma unroll
            for (int j = 0; j < 4; ++j)
                S[i][j] = 2.f * S[i][j] - fk2s[tn * 4 + j];

        const int nb = ch * 64 + tn * 4;
        #pragma unroll
        for (int i = 0; i < 4; ++i) {
            float rm = fmaxf(fmaxf(S[i][0], S[i][1]), fmaxf(S[i][2], S[i][3]));
            rm = fmaxf(rm, __shfl_xor(rm, 1, 64));
            rm = fmaxf(rm, __shfl_xor(rm, 2, 64));
            rm = fmaxf(rm, __shfl_xor(rm, 4, 64));
            rm = fmaxf(rm, __shfl_xor(rm, 8, 64));
            float mnew = fmaxf(mrun[i], rm);
            float alpha = __expf(mrun[i] - mnew);
            float p0 = __expf(S[i][0] - mnew);
            float p1 = __expf(S[i][1] - mnew);
            float p2 = __expf(S[i][2] - mnew);
            float p3 = __expf(S[i][3] - mnew);
            float rs = p0 + p1 + p2 + p3;
            float pdx = p0 * dsp[(nb + 0) * 3 + 0] + p1 * dsp[(nb + 1) * 3 + 0]
                      + p2 * dsp[(nb + 2) * 3 + 0] + p3 * dsp[(nb + 3) * 3 + 0];
            float pdy = p0 * dsp[(nb + 0) * 3 + 1] + p1 * dsp[(nb + 1) * 3 + 1]
                      + p2 * dsp[(nb + 2) * 3 + 1] + p3 * dsp[(nb + 3) * 3 + 1];
            float pdz = p0 * dsp[(nb + 0) * 3 + 2] + p1 * dsp[(nb + 1) * 3 + 2]
                      + p2 * dsp[(nb + 2) * 3 + 2] + p3 * dsp[(nb + 3) * 3 + 2];
            #pragma unroll
            for (int mask = 1; mask <= 8; mask <<= 1) {
                rs  += __shfl_xor(rs,  mask, 64);
                pdx += __shfl_xor(pdx, mask, 64);
                pdy += __shfl_xor(pdy, mask, 64);
                pdz += __shfl_xor(pdz, mask, 64);
            }
            lrun[i] = lrun[i] * alpha + rs;
            orun[i][0] = orun[i][0] * alpha + pdx;
            orun[i][1] = orun[i][1] * alpha + pdy;
            orun[i][2] = orun[i][2] * alpha + pdz;
            mrun[i] = mnew;
        }
        __syncthreads();
    }

    if (tn == 0) {
        #pragma unroll
        for (int i = 0; i < 4; ++i) {
            int g = gbase + tv * 4 + i;
            float il = 1.0f / lrun[i];
            out[0 * NG + g] = orun[i][0] * il;
            out[1 * NG + g] = orun[i][1] * il;
            out[2 * NG + g] = orun[i][2] * il;
        }
    }
}

extern "C" void kernel_launch(void* const* d_in, const int* in_sizes, int n_in,
                              void* d_out, int out_size, void* d_ws, size_t ws_size,
                              hipStream_t stream) {
    const float* kpts  = (const float*)d_in[0];   // (1,512,3)
    const float* disp  = (const float*)d_in[1];   // (1,512,3)
    const float* feats = (const float*)d_in[2];   // (1,125,48,48,48)
    const float* W0    = (const float*)d_in[3];   // (128,128,3,3,3)
    const float* b0    = (const float*)d_in[4];   // (128,)

    float* ws   = (float*)d_ws;
    float* yb   = ws;                              // 128*110592
    float* Wt   = yb + (size_t)NCH * NG;           // 442368
    float* gsum = Wt + 442368;                     // 128
    float* gsq  = gsum + 128;                      // 128
    float* mu   = gsq + 128;                       // 128
    float* ivr  = mu + 128;                        // 128
    float* fkT  = ivr + 128;                       // 128*512
    float* fkn2 = fkT + NCH * NKP;                 // 512

    k_transpose_w<<<1728, 256, 0, stream>>>(W0, Wt);
    hipMemsetAsync(gsum, 0, 256 * sizeof(float), stream);
    k_conv<<<864, 256, 0, stream>>>(feats, Wt, b0, yb, gsum, gsq);
    k_finalize<<<1, 128, 0, stream>>>(gsum, gsq, mu, ivr);
    k_sample<<<NKP, 128, 0, stream>>>(kpts, yb, mu, ivr, fkT, fkn2);
    k_attn<<<1728, 256, 0, stream>>>(yb, mu, ivr, fkT, fkn2, disp, (float*)d_out);
}

// Round 2
// 645.176 us; speedup vs baseline: 2.7781x; 2.7781x over previous
//
#include <hip/hip_runtime.h>
#include <math.h>

#define NG 110592          // 48*48*48
#define NCH 128            // conv channels
#define NKP 512
#define EPSN 1e-5f

typedef _Float16 half8 __attribute__((ext_vector_type(8)));
typedef float floatx4 __attribute__((ext_vector_type(4)));
typedef unsigned short ushort_t;

static __device__ __forceinline__ ushort_t h2u(_Float16 h) {
    union { _Float16 f; ushort_t u; } x; x.f = h; return x.u;
}

// ---------------- W prep: W0[co][ci][tap] fp32 -> Wp[slab=cc*27+tap][h][co][ci'32] f16 bits ----
__global__ __launch_bounds__(256) void k_prep_w(const float* __restrict__ W0,
                                                ushort_t* __restrict__ Wp) {
    int idx = blockIdx.x * 256 + threadIdx.x;     // 884736 total
    int s   = idx >> 13;                          // slab = cc*27 + tap
    int rem = idx & 8191;
    int h   = rem >> 12;                          // 0 = hi, 1 = lo
    int r3  = rem & 4095;
    int co  = r3 >> 5;
    int cip = r3 & 31;
    int cc  = s / 27, tap = s - cc * 27;
    int ci  = cc * 32 + cip;
    float w = W0[co * 3456 + ci * 27 + tap];
    _Float16 hi = (_Float16)w;
    Wp[idx] = (h == 0) ? h2u(hi) : h2u((_Float16)(w - (float)hi));
}

// ---------------- conv3d (implicit GEMM, split-f16 MFMA) + bias + relu + IN stats ----------
// block: 128 vox (4z x 4y x 8x) x 128 co, 4 waves (wave tile 64 vox x 64 co).
// K-loop: 4 ci-chunks of 32 x 27 taps. A (halo) in LDS ci-padded to 40; B from global.
__global__ __launch_bounds__(256, 2) void k_conv(const float* __restrict__ feats,
                                                 const ushort_t* __restrict__ Wp,
                                                 const float* __restrict__ b0,
                                                 float* __restrict__ yout,
                                                 float* __restrict__ gsum,
                                                 float* __restrict__ gsq) {
    __shared__ __align__(16) ushort_t hA0[14400];   // [pos 360][ci' 40] hi
    __shared__ __align__(16) ushort_t hA1[14400];   // lo
    __shared__ float lsum[128], lsq[128];

    const int tid = threadIdx.x;
    const int blk = blockIdx.x;                     // 864: 12z*12y*6x
    const int bz = blk / 72, by = (blk % 72) / 6, bx = blk % 6;
    const int z0 = bz * 4, y0v = by * 4, x0 = bx * 8;

    const int wave = tid >> 6, lane = tid & 63;
    const int ll = lane & 15, kq = lane >> 4;
    const int vhalf = (wave >> 1) * 64, chalf = (wave & 1) * 64;

    if (tid < 128) { lsum[tid] = 0.f; lsq[tid] = 0.f; }

    int abase[4];                                   // byte offsets into halo planes
    #pragma unroll
    for (int mi = 0; mi < 4; ++mi) {
        int v = vhalf + mi * 16 + ll;
        int vz = v >> 5, vy = (v >> 3) & 3, vx = v & 7;
        abase[mi] = (vz * 60 + vy * 10 + vx) * 80 + kq * 16;
    }
    int idxh[4];                                    // half8 indices into a W slab
    #pragma unroll
    for (int ni = 0; ni < 4; ++ni)
        idxh[ni] = (chalf + ni * 16 + ll) * 4 + kq;

    floatx4 acc[4][4];
    const floatx4 zz = {0.f, 0.f, 0.f, 0.f};
    #pragma unroll
    for (int mi = 0; mi < 4; ++mi)
        #pragma unroll
        for (int ni = 0; ni < 4; ++ni) acc[mi][ni] = zz;

    // prologue B prefetch (it = 0)
    half8 Bhn[4], Bln[4];
    {
        const half8* bp = (const half8*)Wp;
        #pragma unroll
        for (int ni = 0; ni < 4; ++ni) { Bhn[ni] = bp[idxh[ni]]; Bln[ni] = bp[idxh[ni] + 512]; }
    }

    const float sc = 2.0f / 47.0f;

    for (int cc = 0; cc < 4; ++cc) {
        __syncthreads();                            // prior chunk's A-reads done
        // ---- stage halo chunk: 360 pos x 32 ci (as 16 ci-pairs), hi/lo split ----
        for (int u = tid; u < 5760; u += 256) {
            int c = u / 360;                        // ci-pair 0..15
            int pos = u - c * 360;                  // 0..359 (consecutive lanes -> coalesced)
            int zi = pos / 60, rem = pos - zi * 60;
            int yi = rem / 10, xi = rem - yi * 10;
            int gz = z0 - 1 + zi, gy = y0v - 1 + yi, gx = x0 - 1 + xi;
            bool inb = ((unsigned)gz < 48u) & ((unsigned)gy < 48u) & ((unsigned)gx < 48u);
            int ci = cc * 32 + 2 * c;
            float v0 = 0.f, v1 = 0.f;
            if (inb) {
                int voxoff = gz * 2304 + gy * 48 + gx;
                v0 = (ci < 125) ? feats[(size_t)ci * NG + voxoff]
                                : ((ci == 125 ? gx : (ci == 126 ? gy : gz)) * sc - 1.0f);
                int ci1 = ci + 1;
                v1 = (ci1 < 125) ? feats[(size_t)ci1 * NG + voxoff]
                                 : ((ci1 == 125 ? gx : (ci1 == 126 ? gy : gz)) * sc - 1.0f);
            }
            _Float16 h0 = (_Float16)v0; _Float16 l0 = (_Float16)(v0 - (float)h0);
            _Float16 h1 = (_Float16)v1; _Float16 l1 = (_Float16)(v1 - (float)h1);
            *(unsigned int*)(&hA0[pos * 40 + 2 * c]) = (unsigned int)h2u(h0) | ((unsigned int)h2u(h1) << 16);
            *(unsigned int*)(&hA1[pos * 40 + 2 * c]) = (unsigned int)h2u(l0) | ((unsigned int)h2u(l1) << 16);
        }
        __syncthreads();

        for (int tap = 0; tap < 27; ++tap) {
            const int it = cc * 27 + tap;
            half8 Bh[4], Bl[4];
            #pragma unroll
            for (int ni = 0; ni < 4; ++ni) { Bh[ni] = Bhn[ni]; Bl[ni] = Bln[ni]; }
            // prefetch next slab's B frags (register double-buffer)
            const int itn = (it + 1 < 108) ? it + 1 : 107;
            const half8* bp = (const half8*)(Wp + (size_t)itn * 8192);
            #pragma unroll
            for (int ni = 0; ni < 4; ++ni) { Bhn[ni] = bp[idxh[ni]]; Bln[ni] = bp[idxh[ni] + 512]; }

            const int tb = (tap / 9) * 4800 + ((tap / 3) % 3) * 800 + (tap % 3) * 80;
            half8 Ah[4], Al[4];
            #pragma unroll
            for (int mi = 0; mi < 4; ++mi) {
                Ah[mi] = *(const half8*)((const char*)hA0 + (abase[mi] + tb));
                Al[mi] = *(const half8*)((const char*)hA1 + (abase[mi] + tb));
            }
            #pragma unroll
            for (int mi = 0; mi < 4; ++mi)
                #pragma unroll
                for (int ni = 0; ni < 4; ++ni) {
                    acc[mi][ni] = __builtin_amdgcn_mfma_f32_16x16x32_f16(Ah[mi], Bh[ni], acc[mi][ni], 0, 0, 0);
                    acc[mi][ni] = __builtin_amdgcn_mfma_f32_16x16x32_f16(Ah[mi], Bl[ni], acc[mi][ni], 0, 0, 0);
                    acc[mi][ni] = __builtin_amdgcn_mfma_f32_16x16x32_f16(Al[mi], Bh[ni], acc[mi][ni], 0, 0, 0);
                }
        }
    }

    // ---- epilogue: bias + relu + store + per-channel stats ----
    #pragma unroll
    for (int ni = 0; ni < 4; ++ni) {
        int co = chalf + ni * 16 + ll;
        float b = b0[co];
        float s = 0.f, q = 0.f;
        #pragma unroll
        for (int mi = 0; mi < 4; ++mi) {
            #pragma unroll
            for (int r = 0; r < 4; ++r) {
                int v = vhalf + mi * 16 + kq * 4 + r;   // C/D: row=(lane>>4)*4+r
                int vz = v >> 5, vy = (v >> 3) & 3, vx = v & 7;
                float val = acc[mi][ni][r] + b;
                val = val > 0.f ? val : 0.f;
                yout[(size_t)co * NG + (z0 + vz) * 2304 + (y0v + vy) * 48 + (x0 + vx)] = val;
                s += val; q += val * val;
            }
        }
        atomicAdd(&lsum[co], s);
        atomicAdd(&lsq[co], q);
    }
    __syncthreads();
    if (tid < 128) { atomicAdd(&gsum[tid], lsum[tid]); atomicAdd(&gsq[tid], lsq[tid]); }
}

// ---------------- finalize instance-norm params ----------------
__global__ void k_finalize(const float* __restrict__ gsum, const float* __restrict__ gsq,
                           float* __restrict__ mu, float* __restrict__ inv) {
    int c = threadIdx.x;
    float m = gsum[c] * (1.0f / NG);
    float v = gsq[c] * (1.0f / NG) - m * m;
    mu[c] = m;
    inv[c] = rsqrtf(v + EPSN);
}

// ---------------- sample fk at keypoints (normalized), and ||fk||^2 ----------------
__global__ __launch_bounds__(128) void k_sample(const float* __restrict__ kpts,
                                                const float* __restrict__ yin,
                                                const float* __restrict__ mu,
                                                const float* __restrict__ inv,
                                                float* __restrict__ fkT,
                                                float* __restrict__ fkn2) {
    __shared__ float red[128];
    const int n = blockIdx.x, c = threadIdx.x;
    float px = kpts[n * 3 + 0], py = kpts[n * 3 + 1], pz = kpts[n * 3 + 2];
    float ix = (px + 1.f) * 0.5f * 47.f;
    float iy = (py + 1.f) * 0.5f * 47.f;
    float iz = (pz + 1.f) * 0.5f * 47.f;
    float xf = floorf(ix), yf = floorf(iy), zf = floorf(iz);
    float wx = ix - xf, wy = iy - yf, wz = iz - zf;
    int x0 = min(max((int)xf, 0), 47), y0 = min(max((int)yf, 0), 47), z0 = min(max((int)zf, 0), 47);
    int x1 = min(x0 + 1, 47), y1 = min(y0 + 1, 47), z1 = min(z0 + 1, 47);

    const float* base = yin + (size_t)c * NG;
    float v000 = base[z0 * 2304 + y0 * 48 + x0];
    float v001 = base[z0 * 2304 + y0 * 48 + x1];
    float v010 = base[z0 * 2304 + y1 * 48 + x0];
    float v011 = base[z0 * 2304 + y1 * 48 + x1];
    float v100 = base[z1 * 2304 + y0 * 48 + x0];
    float v101 = base[z1 * 2304 + y0 * 48 + x1];
    float v110 = base[z1 * 2304 + y1 * 48 + x0];
    float v111 = base[z1 * 2304 + y1 * 48 + x1];

    float val = v000 * (1 - wz) * (1 - wy) * (1 - wx)
              + v001 * (1 - wz) * (1 - wy) * wx
              + v010 * (1 - wz) * wy * (1 - wx)
              + v011 * (1 - wz) * wy * wx
              + v100 * wz * (1 - wy) * (1 - wx)
              + v101 * wz * (1 - wy) * wx
              + v110 * wz * wy * (1 - wx)
              + v111 * wz * wy * wx;

    val = (val - mu[c]) * inv[c];
    fkT[c * NKP + n] = val;
    red[c] = val * val;
    __syncthreads();
    for (int s = 64; s > 0; s >>= 1) {
        if (c < s) red[c] += red[c + s];
        __syncthreads();
    }
    if (c == 0) fkn2[n] = red[0];
}

// ---------------- flash-style softmax over keypoints + disp reduce ----------------
__global__ __launch_bounds__(256) void k_attn(const float* __restrict__ yin,
                                              const float* __restrict__ mu,
                                              const float* __restrict__ inv,
                                              const float* __restrict__ fkT,
                                              const float* __restrict__ fkn2,
                                              const float* __restrict__ disp,
                                              float* __restrict__ out) {
    __shared__ __align__(16) float4 fgs[128 * 16];
    __shared__ __align__(16) float4 fks[128 * 16];
    __shared__ float fk2s[64];
    __shared__ float dsp[1536];

    const int tid = threadIdx.x;
    const int gbase = blockIdx.x * 64;
    const int tv = tid >> 4, tn = tid & 15;

    for (int s = tid; s < 2048; s += 256) {
        int c = s >> 4, v4 = s & 15;
        float4 t = *(const float4*)(yin + (size_t)c * NG + gbase + v4 * 4);
        float m = mu[c], iv = inv[c];
        t.x = (t.x - m) * iv; t.y = (t.y - m) * iv;
        t.z = (t.z - m) * iv; t.w = (t.w - m) * iv;
        fgs[s] = t;
    }
    for (int s = tid; s < 1536; s += 256) dsp[s] = disp[s];

    float mrun[4], lrun[4], orun[4][3];
    #pragma unroll
    for (int i = 0; i < 4; ++i) {
        mrun[i] = -1e30f; lrun[i] = 0.f;
        orun[i][0] = 0.f; orun[i][1] = 0.f; orun[i][2] = 0.f;
    }
    __syncthreads();

    for (int ch = 0; ch < 8; ++ch) {
        for (int s = tid; s < 2048; s += 256) {
            int c = s >> 4, j4 = s & 15;
            fks[s] = *(const float4*)(fkT + c * NKP + ch * 64 + j4 * 4);
        }
        if (tid < 64) fk2s[tid] = fkn2[ch * 64 + tid];
        __syncthreads();

        float S[4][4];
        #pragma unroll
        for (int i = 0; i < 4; ++i)
            #pragma unroll
            for (int j = 0; j < 4; ++j) S[i][j] = 0.f;

        for (int c = 0; c < 128; ++c) {
            float4 a = fgs[c * 16 + tv];
            float4 b = fks[c * 16 + tn];
            S[0][0] = fmaf(a.x, b.x, S[0][0]); S[0][1] = fmaf(a.x, b.y, S[0][1]);
            S[0][2] = fmaf(a.x, b.z, S[0][2]); S[0][3] = fmaf(a.x, b.w, S[0][3]);
            S[1][0] = fmaf(a.y, b.x, S[1][0]); S[1][1] = fmaf(a.y, b.y, S[1][1]);
            S[1][2] = fmaf(a.y, b.z, S[1][2]); S[1][3] = fmaf(a.y, b.w, S[1][3]);
            S[2][0] = fmaf(a.z, b.x, S[2][0]); S[2][1] = fmaf(a.z, b.y, S[2][1]);
            S[2][2] = fmaf(a.z, b.z, S[2][2]); S[2][3] = fmaf(a.z, b.w, S[2][3]);
            S[3][0] = fmaf(a.w, b.x, S[3][0]); S[3][1] = fmaf(a.w, b.y, S[3][1]);
            S[3][2] = fmaf(a.w, b.z, S[3][2]); S[3][3] = fmaf(a.w, b.w, S[3][3]);
        }

        #pragma unroll
        for (int i = 0; i < 4; ++i)
            #pragma unroll
            for (int j = 0; j < 4; ++j)
                S[i][j] = 2.f * S[i][j] - fk2s[tn * 4 + j];

        const int nb = ch * 64 + tn * 4;
        #pragma unroll
        for (int i = 0; i < 4; ++i) {
            float rm = fmaxf(fmaxf(S[i][0], S[i][1]), fmaxf(S[i][2], S[i][3]));
            rm = fmaxf(rm, __shfl_xor(rm, 1, 64));
            rm = fmaxf(rm, __shfl_xor(rm, 2, 64));
            rm = fmaxf(rm, __shfl_xor(rm, 4, 64));
            rm = fmaxf(rm, __shfl_xor(rm, 8, 64));
            float mnew = fmaxf(mrun[i], rm);
            float alpha = __expf(mrun[i] - mnew);
            float p0 = __expf(S[i][0] - mnew);
            float p1 = __expf(S[i][1] - mnew);
            float p2 = __expf(S[i][2] - mnew);
            float p3 = __expf(S[i][3] - mnew);
            float rs = p0 + p1 + p2 + p3;
            float pdx = p0 * dsp[(nb + 0) * 3 + 0] + p1 * dsp[(nb + 1) * 3 + 0]
                      + p2 * dsp[(nb + 2) * 3 + 0] + p3 * dsp[(nb + 3) * 3 + 0];
            float pdy = p0 * dsp[(nb + 0) * 3 + 1] + p1 * dsp[(nb + 1) * 3 + 1]
                      + p2 * dsp[(nb + 2) * 3 + 1] + p3 * dsp[(nb + 3) * 3 + 1];
            float pdz = p0 * dsp[(nb + 0) * 3 + 2] + p1 * dsp[(nb + 1) * 3 + 2]
                      + p2 * dsp[(nb + 2) * 3 + 2] + p3 * dsp[(nb + 3) * 3 + 2];
            #pragma unroll
            for (int mask = 1; mask <= 8; mask <<= 1) {
                rs  += __shfl_xor(rs,  mask, 64);
                pdx += __shfl_xor(pdx, mask, 64);
                pdy += __shfl_xor(pdy, mask, 64);
                pdz += __shfl_xor(pdz, mask, 64);
            }
            lrun[i] = lrun[i] * alpha + rs;
            orun[i][0] = orun[i][0] * alpha + pdx;
            orun[i][1] = orun[i][1] * alpha + pdy;
            orun[i][2] = orun[i][2] * alpha + pdz;
            mrun[i] = mnew;
        }
        __syncthreads();
    }

    if (tn == 0) {
        #pragma unroll
        for (int i = 0; i < 4; ++i) {
            int g = gbase + tv * 4 + i;
            float il = 1.0f / lrun[i];
            out[0 * NG + g] = orun[i][0] * il;
            out[1 * NG + g] = orun[i][1] * il;
            out[2 * NG + g] = orun[i][2] * il;
        }
    }
}

extern "C" void kernel_launch(void* const* d_in, const int* in_sizes, int n_in,
                              void* d_out, int out_size, void* d_ws, size_t ws_size,
                              hipStream_t stream) {
    const float* kpts  = (const float*)d_in[0];   // (1,512,3)
    const float* disp  = (const float*)d_in[1];   // (1,512,3)
    const float* feats = (const float*)d_in[2];   // (1,125,48,48,48)
    const float* W0    = (const float*)d_in[3];   // (128,128,3,3,3)
    const float* b0    = (const float*)d_in[4];   // (128,)

    float* ws = (float*)d_ws;
    float*    yb   = ws;                                   // 128*110592 floats
    ushort_t* Wp   = (ushort_t*)(yb + (size_t)NCH * NG);   // 884736 ushorts (= 442368 float slots)
    float*    gsum = yb + (size_t)NCH * NG + 442368;       // 128
    float*    gsq  = gsum + 128;                           // 128
    float*    mu   = gsq + 128;                            // 128
    float*    ivr  = mu + 128;                             // 128
    float*    fkT  = ivr + 128;                            // 128*512
    float*    fkn2 = fkT + NCH * NKP;                      // 512

    k_prep_w<<<3456, 256, 0, stream>>>(W0, Wp);
    hipMemsetAsync(gsum, 0, 256 * sizeof(float), stream);
    k_conv<<<864, 256, 0, stream>>>(feats, Wp, b0, yb, gsum, gsq);
    k_finalize<<<1, 128, 0, stream>>>(gsum, gsq, mu, ivr);
    k_sample<<<NKP, 128, 0, stream>>>(kpts, yb, mu, ivr, fkT, fkn2);
    k_attn<<<1728, 256, 0, stream>>>(yb, mu, ivr, fkT, fkn2, disp, (float*)d_out);
}

// Round 3
// 581.580 us; speedup vs baseline: 3.0818x; 1.1094x over previous
//
#include <hip/hip_runtime.h>
#include <math.h>

#define NG 110592          // 48*48*48
#define NCH 128            // conv channels
#define NKP 512
#define EPSN 1e-5f

typedef _Float16 half8 __attribute__((ext_vector_type(8)));
typedef float floatx4 __attribute__((ext_vector_type(4)));
typedef unsigned short ushort_t;

static __device__ __forceinline__ ushort_t h2u(_Float16 h) {
    union { _Float16 f; ushort_t u; } x; x.f = h; return x.u;
}

// ---------------- W prep: W0[co][ci][tap] fp32 -> Wp[slab=cc*27+tap][h][co][ci'32] f16 bits ----
__global__ __launch_bounds__(256) void k_prep_w(const float* __restrict__ W0,
                                                ushort_t* __restrict__ Wp) {
    int idx = blockIdx.x * 256 + threadIdx.x;     // 884736 total
    int s   = idx >> 13;                          // slab = cc*27 + tap
    int rem = idx & 8191;
    int h   = rem >> 12;                          // 0 = hi, 1 = lo
    int r3  = rem & 4095;
    int co  = r3 >> 5;
    int cip = r3 & 31;
    int cc  = s / 27, tap = s - cc * 27;
    int ci  = cc * 32 + cip;
    float w = W0[co * 3456 + ci * 27 + tap];
    _Float16 hi = (_Float16)w;
    Wp[idx] = (h == 0) ? h2u(hi) : h2u((_Float16)(w - (float)hi));
}

// ---------------- conv3d (implicit GEMM, 2-pass split-f16 MFMA) + bias + relu + IN stats ----
// block: 128 vox (4z x 4y x 8x) x 128 co, 4 waves (wave tile 64 vox x 64 co).
// K-loop: 4 ci-chunks of 32 x 27 taps. A (halo, hi only) in LDS ci-padded to 40; B from global.
// 2-pass: acc += Ah*Bh + Ah*Bl  (activation-lo term dropped, ~2^-12 relative)
__global__ __launch_bounds__(256, 4) void k_conv(const float* __restrict__ feats,
                                                 const ushort_t* __restrict__ Wp,
                                                 const float* __restrict__ b0,
                                                 float* __restrict__ yout,
                                                 float* __restrict__ gsum,
                                                 float* __restrict__ gsq) {
    __shared__ __align__(16) ushort_t hA0[14400];   // [pos 360][ci' 40] hi halves
    __shared__ float lsum[128], lsq[128];

    const int tid = threadIdx.x;
    const int blk = blockIdx.x;                     // 864: 12z*12y*6x
    const int bz = blk / 72, by = (blk % 72) / 6, bx = blk % 6;
    const int z0 = bz * 4, y0v = by * 4, x0 = bx * 8;

    const int wave = tid >> 6, lane = tid & 63;
    const int ll = lane & 15, kq = lane >> 4;
    const int vhalf = (wave >> 1) * 64, chalf = (wave & 1) * 64;

    if (tid < 128) { lsum[tid] = 0.f; lsq[tid] = 0.f; }

    int abase[4];                                   // byte offsets into halo plane
    #pragma unroll
    for (int mi = 0; mi < 4; ++mi) {
        int v = vhalf + mi * 16 + ll;
        int vz = v >> 5, vy = (v >> 3) & 3, vx = v & 7;
        abase[mi] = (vz * 60 + vy * 10 + vx) * 80 + kq * 16;
    }
    int idxh[4];                                    // half8 indices into a W slab
    #pragma unroll
    for (int ni = 0; ni < 4; ++ni)
        idxh[ni] = (chalf + ni * 16 + ll) * 4 + kq;

    floatx4 acc[4][4];
    const floatx4 zz = {0.f, 0.f, 0.f, 0.f};
    #pragma unroll
    for (int mi = 0; mi < 4; ++mi)
        #pragma unroll
        for (int ni = 0; ni < 4; ++ni) acc[mi][ni] = zz;

    const float sc = 2.0f / 47.0f;

    for (int cc = 0; cc < 4; ++cc) {
        __syncthreads();                            // prior chunk's A-reads done
        // ---- stage halo chunk: lane converts 8 ci for one pos, single b128 write ----
        for (int u = tid; u < 1440; u += 256) {
            int c8 = u / 360;                       // ci-octet 0..3
            int pos = u - c8 * 360;                 // consecutive lanes -> coalesced
            int zi = pos / 60, rem = pos - zi * 60;
            int yi = rem / 10, xi = rem - yi * 10;
            int gz = z0 - 1 + zi, gy = y0v - 1 + yi, gx = x0 - 1 + xi;
            bool inb = ((unsigned)gz < 48u) & ((unsigned)gy < 48u) & ((unsigned)gx < 48u);
            int cib = cc * 32 + c8 * 8;
            half8 h;
            if (inb) {
                int voxoff = gz * 2304 + gy * 48 + gx;
                #pragma unroll
                for (int j = 0; j < 8; ++j) {
                    int ci = cib + j;
                    float v = (ci < 125) ? feats[(size_t)ci * NG + voxoff]
                                         : ((ci == 125 ? gx : (ci == 126 ? gy : gz)) * sc - 1.0f);
                    h[j] = (_Float16)v;
                }
            } else {
                #pragma unroll
                for (int j = 0; j < 8; ++j) h[j] = (_Float16)0.f;
            }
            *(half8*)(&hA0[pos * 40 + c8 * 8]) = h;
        }
        __syncthreads();

        for (int tap = 0; tap < 27; ++tap) {
            const int it = cc * 27 + tap;
            const half8* bp = (const half8*)(Wp + (size_t)it * 8192);

            const int tb = (tap / 9) * 4800 + ((tap / 3) % 3) * 800 + (tap % 3) * 80;
            half8 Ah[4];
            #pragma unroll
            for (int mi = 0; mi < 4; ++mi)
                Ah[mi] = *(const half8*)((const char*)hA0 + (abase[mi] + tb));

            half8 Bh[4];
            #pragma unroll
            for (int ni = 0; ni < 4; ++ni) Bh[ni] = bp[idxh[ni]];
            #pragma unroll
            for (int mi = 0; mi < 4; ++mi)
                #pragma unroll
                for (int ni = 0; ni < 4; ++ni)
                    acc[mi][ni] = __builtin_amdgcn_mfma_f32_16x16x32_f16(Ah[mi], Bh[ni], acc[mi][ni], 0, 0, 0);

            half8 Bl[4];
            #pragma unroll
            for (int ni = 0; ni < 4; ++ni) Bl[ni] = bp[idxh[ni] + 512];
            #pragma unroll
            for (int mi = 0; mi < 4; ++mi)
                #pragma unroll
                for (int ni = 0; ni < 4; ++ni)
                    acc[mi][ni] = __builtin_amdgcn_mfma_f32_16x16x32_f16(Ah[mi], Bl[ni], acc[mi][ni], 0, 0, 0);
        }
    }

    // ---- epilogue: bias + relu + store + per-channel stats ----
    #pragma unroll
    for (int ni = 0; ni < 4; ++ni) {
        int co = chalf + ni * 16 + ll;
        float b = b0[co];
        float s = 0.f, q = 0.f;
        #pragma unroll
        for (int mi = 0; mi < 4; ++mi) {
            #pragma unroll
            for (int r = 0; r < 4; ++r) {
                int v = vhalf + mi * 16 + kq * 4 + r;   // C/D: row=(lane>>4)*4+r
                int vz = v >> 5, vy = (v >> 3) & 3, vx = v & 7;
                float val = acc[mi][ni][r] + b;
                val = val > 0.f ? val : 0.f;
                yout[(size_t)co * NG + (z0 + vz) * 2304 + (y0v + vy) * 48 + (x0 + vx)] = val;
                s += val; q += val * val;
            }
        }
        atomicAdd(&lsum[co], s);
        atomicAdd(&lsq[co], q);
    }
    __syncthreads();
    if (tid < 128) { atomicAdd(&gsum[tid], lsum[tid]); atomicAdd(&gsq[tid], lsq[tid]); }
}

// ---------------- finalize instance-norm params ----------------
__global__ void k_finalize(const float* __restrict__ gsum, const float* __restrict__ gsq,
                           float* __restrict__ mu, float* __restrict__ inv) {
    int c = threadIdx.x;
    float m = gsum[c] * (1.0f / NG);
    float v = gsq[c] * (1.0f / NG) - m * m;
    mu[c] = m;
    inv[c] = rsqrtf(v + EPSN);
}

// ---------------- sample fk at keypoints (normalized), and ||fk||^2 ----------------
__global__ __launch_bounds__(128) void k_sample(const float* __restrict__ kpts,
                                                const float* __restrict__ yin,
                                                const float* __restrict__ mu,
                                                const float* __restrict__ inv,
                                                float* __restrict__ fkT,
                                                float* __restrict__ fkn2) {
    __shared__ float red[128];
    const int n = blockIdx.x, c = threadIdx.x;
    float px = kpts[n * 3 + 0], py = kpts[n * 3 + 1], pz = kpts[n * 3 + 2];
    float ix = (px + 1.f) * 0.5f * 47.f;
    float iy = (py + 1.f) * 0.5f * 47.f;
    float iz = (pz + 1.f) * 0.5f * 47.f;
    float xf = floorf(ix), yf = floorf(iy), zf = floorf(iz);
    float wx = ix - xf, wy = iy - yf, wz = iz - zf;
    int x0 = min(max((int)xf, 0), 47), y0 = min(max((int)yf, 0), 47), z0 = min(max((int)zf, 0), 47);
    int x1 = min(x0 + 1, 47), y1 = min(y0 + 1, 47), z1 = min(z0 + 1, 47);

    const float* base = yin + (size_t)c * NG;
    float v000 = base[z0 * 2304 + y0 * 48 + x0];
    float v001 = base[z0 * 2304 + y0 * 48 + x1];
    float v010 = base[z0 * 2304 + y1 * 48 + x0];
    float v011 = base[z0 * 2304 + y1 * 48 + x1];
    float v100 = base[z1 * 2304 + y0 * 48 + x0];
    float v101 = base[z1 * 2304 + y0 * 48 + x1];
    float v110 = base[z1 * 2304 + y1 * 48 + x0];
    float v111 = base[z1 * 2304 + y1 * 48 + x1];

    float val = v000 * (1 - wz) * (1 - wy) * (1 - wx)
              + v001 * (1 - wz) * (1 - wy) * wx
              + v010 * (1 - wz) * wy * (1 - wx)
              + v011 * (1 - wz) * wy * wx
              + v100 * wz * (1 - wy) * (1 - wx)
              + v101 * wz * (1 - wy) * wx
              + v110 * wz * wy * (1 - wx)
              + v111 * wz * wy * wx;

    val = (val - mu[c]) * inv[c];
    fkT[c * NKP + n] = val;
    red[c] = val * val;
    __syncthreads();
    for (int s = 64; s > 0; s >>= 1) {
        if (c < s) red[c] += red[c + s];
        __syncthreads();
    }
    if (c == 0) fkn2[n] = red[0];
}

// ---------------- flash-style softmax over keypoints + disp reduce ----------------
__global__ __launch_bounds__(256) void k_attn(const float* __restrict__ yin,
                                              const float* __restrict__ mu,
                                              const float* __restrict__ inv,
                                              const float* __restrict__ fkT,
                                              const float* __restrict__ fkn2,
                                              const float* __restrict__ disp,
                                              float* __restrict__ out) {
    __shared__ __align__(16) float4 fgs[128 * 16];
    __shared__ __align__(16) float4 fks[128 * 16];
    __shared__ float fk2s[64];
    __shared__ float dsp[1536];

    const int tid = threadIdx.x;
    const int gbase = blockIdx.x * 64;
    const int tv = tid >> 4, tn = tid & 15;

    for (int s = tid; s < 2048; s += 256) {
        int c = s >> 4, v4 = s & 15;
        float4 t = *(const float4*)(yin + (size_t)c * NG + gbase + v4 * 4);
        float m = mu[c], iv = inv[c];
        t.x = (t.x - m) * iv; t.y = (t.y - m) * iv;
        t.z = (t.z - m) * iv; t.w = (t.w - m) * iv;
        fgs[s] = t;
    }
    for (int s = tid; s < 1536; s += 256) dsp[s] = disp[s];

    float mrun[4], lrun[4], orun[4][3];
    #pragma unroll
    for (int i = 0; i < 4; ++i) {
        mrun[i] = -1e30f; lrun[i] = 0.f;
        orun[i][0] = 0.f; orun[i][1] = 0.f; orun[i][2] = 0.f;
    }
    __syncthreads();

    for (int ch = 0; ch < 8; ++ch) {
        for (int s = tid; s < 2048; s += 256) {
            int c = s >> 4, j4 = s & 15;
            fks[s] = *(const float4*)(fkT + c * NKP + ch * 64 + j4 * 4);
        }
        if (tid < 64) fk2s[tid] = fkn2[ch * 64 + tid];
        __syncthreads();

        float S[4][4];
        #pragma unroll
        for (int i = 0; i < 4; ++i)
            #pragma unroll
            for (int j = 0; j < 4; ++j) S[i][j] = 0.f;

        for (int c = 0; c < 128; ++c) {
            float4 a = fgs[c * 16 + tv];
            float4 b = fks[c * 16 + tn];
            S[0][0] = fmaf(a.x, b.x, S[0][0]); S[0][1] = fmaf(a.x, b.y, S[0][1]);
            S[0][2] = fmaf(a.x, b.z, S[0][2]); S[0][3] = fmaf(a.x, b.w, S[0][3]);
            S[1][0] = fmaf(a.y, b.x, S[1][0]); S[1][1] = fmaf(a.y, b.y, S[1][1]);
            S[1][2] = fmaf(a.y, b.z, S[1][2]); S[1][3] = fmaf(a.y, b.w, S[1][3]);
            S[2][0] = fmaf(a.z, b.x, S[2][0]); S[2][1] = fmaf(a.z, b.y, S[2][1]);
            S[2][2] = fmaf(a.z, b.z, S[2][2]); S[2][3] = fmaf(a.z, b.w, S[2][3]);
            S[3][0] = fmaf(a.w, b.x, S[3][0]); S[3][1] = fmaf(a.w, b.y, S[3][1]);
            S[3][2] = fmaf(a.w, b.z, S[3][2]); S[3][3] = fmaf(a.w, b.w, S[3][3]);
        }

        #pragma unroll
        for (int i = 0; i < 4; ++i)
            #pragma unroll
            for (int j = 0; j < 4; ++j)
                S[i][j] = 2.f * S[i][j] - fk2s[tn * 4 + j];

        const int nb = ch * 64 + tn * 4;
        #pragma unroll
        for (int i = 0; i < 4; ++i) {
            float rm = fmaxf(fmaxf(S[i][0], S[i][1]), fmaxf(S[i][2], S[i][3]));
            rm = fmaxf(rm, __shfl_xor(rm, 1, 64));
            rm = fmaxf(rm, __shfl_xor(rm, 2, 64));
            rm = fmaxf(rm, __shfl_xor(rm, 4, 64));
            rm = fmaxf(rm, __shfl_xor(rm, 8, 64));
            float mnew = fmaxf(mrun[i], rm);
            float alpha = __expf(mrun[i] - mnew);
            float p0 = __expf(S[i][0] - mnew);
            float p1 = __expf(S[i][1] - mnew);
            float p2 = __expf(S[i][2] - mnew);
            float p3 = __expf(S[i][3] - mnew);
            float rs = p0 + p1 + p2 + p3;
            float pdx = p0 * dsp[(nb + 0) * 3 + 0] + p1 * dsp[(nb + 1) * 3 + 0]
                      + p2 * dsp[(nb + 2) * 3 + 0] + p3 * dsp[(nb + 3) * 3 + 0];
            float pdy = p0 * dsp[(nb + 0) * 3 + 1] + p1 * dsp[(nb + 1) * 3 + 1]
                      + p2 * dsp[(nb + 2) * 3 + 1] + p3 * dsp[(nb + 3) * 3 + 1];
            float pdz = p0 * dsp[(nb + 0) * 3 + 2] + p1 * dsp[(nb + 1) * 3 + 2]
                      + p2 * dsp[(nb + 2) * 3 + 2] + p3 * dsp[(nb + 3) * 3 + 2];
            #pragma unroll
            for (int mask = 1; mask <= 8; mask <<= 1) {
                rs  += __shfl_xor(rs,  mask, 64);
                pdx += __shfl_xor(pdx, mask, 64);
                pdy += __shfl_xor(pdy, mask, 64);
                pdz += __shfl_xor(pdz, mask, 64);
            }
            lrun[i] = lrun[i] * alpha + rs;
            orun[i][0] = orun[i][0] * alpha + pdx;
            orun[i][1] = orun[i][1] * alpha + pdy;
            orun[i][2] = orun[i][2] * alpha + pdz;
            mrun[i] = mnew;
        }
        __syncthreads();
    }

    if (tn == 0) {
        #pragma unroll
        for (int i = 0; i < 4; ++i) {
            int g = gbase + tv * 4 + i;
            float il = 1.0f / lrun[i];
            out[0 * NG + g] = orun[i][0] * il;
            out[1 * NG + g] = orun[i][1] * il;
            out[2 * NG + g] = orun[i][2] * il;
        }
    }
}

extern "C" void kernel_launch(void* const* d_in, const int* in_sizes, int n_in,
                              void* d_out, int out_size, void* d_ws, size_t ws_size,
                              hipStream_t stream) {
    const float* kpts  = (const float*)d_in[0];   // (1,512,3)
    const float* disp  = (const float*)d_in[1];   // (1,512,3)
    const float* feats = (const float*)d_in[2];   // (1,125,48,48,48)
    const float* W0    = (const float*)d_in[3];   // (128,128,3,3,3)
    const float* b0    = (const float*)d_in[4];   // (128,)

    float* ws = (float*)d_ws;
    float*    yb   = ws;                                   // 128*110592 floats
    ushort_t* Wp   = (ushort_t*)(yb + (size_t)NCH * NG);   // 884736 ushorts (= 442368 float slots)
    float*    gsum = yb + (size_t)NCH * NG + 442368;       // 128
    float*    gsq  = gsum + 128;                           // 128
    float*    mu   = gsq + 128;                            // 128
    float*    ivr  = mu + 128;                             // 128
    float*    fkT  = ivr + 128;                            // 128*512
    float*    fkn2 = fkT + NCH * NKP;                      // 512

    k_prep_w<<<3456, 256, 0, stream>>>(W0, Wp);
    hipMemsetAsync(gsum, 0, 256 * sizeof(float), stream);
    k_conv<<<864, 256, 0, stream>>>(feats, Wp, b0, yb, gsum, gsq);
    k_finalize<<<1, 128, 0, stream>>>(gsum, gsq, mu, ivr);
    k_sample<<<NKP, 128, 0, stream>>>(kpts, yb, mu, ivr, fkT, fkn2);
    k_attn<<<1728, 256, 0, stream>>>(yb, mu, ivr, fkT, fkn2, disp, (float*)d_out);
}

// Round 4
// 409.744 us; speedup vs baseline: 4.3743x; 1.4194x over previous
//
#include <hip/hip_runtime.h>
#include <math.h>

#define NG 110592          // 48*48*48
#define NCH 128            // conv channels
#define NKP 512
#define EPSN 1e-5f

typedef _Float16 half8 __attribute__((ext_vector_type(8)));
typedef float floatx4 __attribute__((ext_vector_type(4)));
typedef unsigned short ushort_t;

static __device__ __forceinline__ ushort_t h2u(_Float16 h) {
    union { _Float16 f; ushort_t u; } x; x.f = h; return x.u;
}

// ---------------- W prep: W0[co][ci][tap] fp32 -> Wp[slab=cc*27+tap][h][co][ci'32] f16 bits ----
__global__ __launch_bounds__(256) void k_prep_w(const float* __restrict__ W0,
                                                ushort_t* __restrict__ Wp) {
    int idx = blockIdx.x * 256 + threadIdx.x;     // 884736 total
    int s   = idx >> 13;                          // slab = cc*27 + tap
    int rem = idx & 8191;
    int h   = rem >> 12;                          // 0 = hi, 1 = lo
    int r3  = rem & 4095;
    int co  = r3 >> 5;
    int cip = r3 & 31;
    int cc  = s / 27, tap = s - cc * 27;
    int ci  = cc * 32 + cip;
    float w = W0[co * 3456 + ci * 27 + tap];
    _Float16 hi = (_Float16)w;
    Wp[idx] = (h == 0) ? h2u(hi) : h2u((_Float16)(w - (float)hi));
}

// ---------------- conv3d (implicit GEMM, 2-pass split-f16 MFMA) + bias + relu + IN stats ----
__global__ __launch_bounds__(256, 4) void k_conv(const float* __restrict__ feats,
                                                 const ushort_t* __restrict__ Wp,
                                                 const float* __restrict__ b0,
                                                 float* __restrict__ yout,
                                                 float* __restrict__ gsum,
                                                 float* __restrict__ gsq) {
    __shared__ __align__(16) ushort_t hA0[14400];   // [pos 360][ci' 40] hi halves
    __shared__ float lsum[128], lsq[128];

    const int tid = threadIdx.x;
    const int blk = blockIdx.x;                     // 864: 12z*12y*6x
    const int bz = blk / 72, by = (blk % 72) / 6, bx = blk % 6;
    const int z0 = bz * 4, y0v = by * 4, x0 = bx * 8;

    const int wave = tid >> 6, lane = tid & 63;
    const int ll = lane & 15, kq = lane >> 4;
    const int vhalf = (wave >> 1) * 64, chalf = (wave & 1) * 64;

    if (tid < 128) { lsum[tid] = 0.f; lsq[tid] = 0.f; }

    int abase[4];
    #pragma unroll
    for (int mi = 0; mi < 4; ++mi) {
        int v = vhalf + mi * 16 + ll;
        int vz = v >> 5, vy = (v >> 3) & 3, vx = v & 7;
        abase[mi] = (vz * 60 + vy * 10 + vx) * 80 + kq * 16;
    }
    int idxh[4];
    #pragma unroll
    for (int ni = 0; ni < 4; ++ni)
        idxh[ni] = (chalf + ni * 16 + ll) * 4 + kq;

    floatx4 acc[4][4];
    const floatx4 zz = {0.f, 0.f, 0.f, 0.f};
    #pragma unroll
    for (int mi = 0; mi < 4; ++mi)
        #pragma unroll
        for (int ni = 0; ni < 4; ++ni) acc[mi][ni] = zz;

    const float sc = 2.0f / 47.0f;

    for (int cc = 0; cc < 4; ++cc) {
        __syncthreads();
        for (int u = tid; u < 1440; u += 256) {
            int c8 = u / 360;
            int pos = u - c8 * 360;
            int zi = pos / 60, rem = pos - zi * 60;
            int yi = rem / 10, xi = rem - yi * 10;
            int gz = z0 - 1 + zi, gy = y0v - 1 + yi, gx = x0 - 1 + xi;
            bool inb = ((unsigned)gz < 48u) & ((unsigned)gy < 48u) & ((unsigned)gx < 48u);
            int cib = cc * 32 + c8 * 8;
            half8 h;
            if (inb) {
                int voxoff = gz * 2304 + gy * 48 + gx;
                #pragma unroll
                for (int j = 0; j < 8; ++j) {
                    int ci = cib + j;
                    float v = (ci < 125) ? feats[(size_t)ci * NG + voxoff]
                                         : ((ci == 125 ? gx : (ci == 126 ? gy : gz)) * sc - 1.0f);
                    h[j] = (_Float16)v;
                }
            } else {
                #pragma unroll
                for (int j = 0; j < 8; ++j) h[j] = (_Float16)0.f;
            }
            *(half8*)(&hA0[pos * 40 + c8 * 8]) = h;
        }
        __syncthreads();

        for (int tap = 0; tap < 27; ++tap) {
            const int it = cc * 27 + tap;
            const half8* bp = (const half8*)(Wp + (size_t)it * 8192);

            const int tb = (tap / 9) * 4800 + ((tap / 3) % 3) * 800 + (tap % 3) * 80;
            half8 Ah[4];
            #pragma unroll
            for (int mi = 0; mi < 4; ++mi)
                Ah[mi] = *(const half8*)((const char*)hA0 + (abase[mi] + tb));

            half8 Bh[4];
            #pragma unroll
            for (int ni = 0; ni < 4; ++ni) Bh[ni] = bp[idxh[ni]];
            #pragma unroll
            for (int mi = 0; mi < 4; ++mi)
                #pragma unroll
                for (int ni = 0; ni < 4; ++ni)
                    acc[mi][ni] = __builtin_amdgcn_mfma_f32_16x16x32_f16(Ah[mi], Bh[ni], acc[mi][ni], 0, 0, 0);

            half8 Bl[4];
            #pragma unroll
            for (int ni = 0; ni < 4; ++ni) Bl[ni] = bp[idxh[ni] + 512];
            #pragma unroll
            for (int mi = 0; mi < 4; ++mi)
                #pragma unroll
                for (int ni = 0; ni < 4; ++ni)
                    acc[mi][ni] = __builtin_amdgcn_mfma_f32_16x16x32_f16(Ah[mi], Bl[ni], acc[mi][ni], 0, 0, 0);
        }
    }

    #pragma unroll
    for (int ni = 0; ni < 4; ++ni) {
        int co = chalf + ni * 16 + ll;
        float b = b0[co];
        float s = 0.f, q = 0.f;
        #pragma unroll
        for (int mi = 0; mi < 4; ++mi) {
            #pragma unroll
            for (int r = 0; r < 4; ++r) {
                int v = vhalf + mi * 16 + kq * 4 + r;
                int vz = v >> 5, vy = (v >> 3) & 3, vx = v & 7;
                float val = acc[mi][ni][r] + b;
                val = val > 0.f ? val : 0.f;
                yout[(size_t)co * NG + (z0 + vz) * 2304 + (y0v + vy) * 48 + (x0 + vx)] = val;
                s += val; q += val * val;
            }
        }
        atomicAdd(&lsum[co], s);
        atomicAdd(&lsq[co], q);
    }
    __syncthreads();
    if (tid < 128) { atomicAdd(&gsum[tid], lsum[tid]); atomicAdd(&gsq[tid], lsq[tid]); }
}

// ---------------- finalize instance-norm params ----------------
__global__ void k_finalize(const float* __restrict__ gsum, const float* __restrict__ gsq,
                           float* __restrict__ mu, float* __restrict__ inv) {
    int c = threadIdx.x;
    float m = gsum[c] * (1.0f / NG);
    float v = gsq[c] * (1.0f / NG) - m * m;
    mu[c] = m;
    inv[c] = rsqrtf(v + EPSN);
}

// ---------------- sample fk at keypoints: normalized, split-f16, A-frag layout + ||fk||^2 ----
__global__ __launch_bounds__(128) void k_sample(const float* __restrict__ kpts,
                                                const float* __restrict__ yin,
                                                const float* __restrict__ mu,
                                                const float* __restrict__ inv,
                                                ushort_t* __restrict__ fkH,
                                                ushort_t* __restrict__ fkL,
                                                float* __restrict__ fkn2) {
    __shared__ float red[128];
    const int n = blockIdx.x, c = threadIdx.x;
    float px = kpts[n * 3 + 0], py = kpts[n * 3 + 1], pz = kpts[n * 3 + 2];
    float ix = (px + 1.f) * 0.5f * 47.f;
    float iy = (py + 1.f) * 0.5f * 47.f;
    float iz = (pz + 1.f) * 0.5f * 47.f;
    float xf = floorf(ix), yf = floorf(iy), zf = floorf(iz);
    float wx = ix - xf, wy = iy - yf, wz = iz - zf;
    int x0 = min(max((int)xf, 0), 47), y0 = min(max((int)yf, 0), 47), z0 = min(max((int)zf, 0), 47);
    int x1 = min(x0 + 1, 47), y1 = min(y0 + 1, 47), z1 = min(z0 + 1, 47);

    const float* base = yin + (size_t)c * NG;
    float v000 = base[z0 * 2304 + y0 * 48 + x0];
    float v001 = base[z0 * 2304 + y0 * 48 + x1];
    float v010 = base[z0 * 2304 + y1 * 48 + x0];
    float v011 = base[z0 * 2304 + y1 * 48 + x1];
    float v100 = base[z1 * 2304 + y0 * 48 + x0];
    float v101 = base[z1 * 2304 + y0 * 48 + x1];
    float v110 = base[z1 * 2304 + y1 * 48 + x0];
    float v111 = base[z1 * 2304 + y1 * 48 + x1];

    float val = v000 * (1 - wz) * (1 - wy) * (1 - wx)
              + v001 * (1 - wz) * (1 - wy) * wx
              + v010 * (1 - wz) * wy * (1 - wx)
              + v011 * (1 - wz) * wy * wx
              + v100 * wz * (1 - wy) * (1 - wx)
              + v101 * wz * (1 - wy) * wx
              + v110 * wz * wy * (1 - wx)
              + v111 * wz * wy * wx;

    val = (val - mu[c]) * inv[c];
    _Float16 h = (_Float16)val;
    fkH[n * 128 + c] = h2u(h);
    fkL[n * 128 + c] = h2u((_Float16)(val - (float)h));
    red[c] = val * val;
    __syncthreads();
    for (int s = 64; s > 0; s >>= 1) {
        if (c < s) red[c] += red[c + s];
        __syncthreads();
    }
    if (c == 0) fkn2[n] = red[0];
}

// ---------------- MFMA flash-attention over keypoints + disp reduce ----------------
// block: 64 voxels, 4 waves; wave w owns keys [w*128, w*128+128). keys=M (A, global),
// vox=N (B, LDS, ch padded 128->136). 3-pass split-f16: AhBh + AhBl + AlBh.
__global__ __launch_bounds__(256, 2) void k_attn(const float* __restrict__ yb,
                                                 const float* __restrict__ mu,
                                                 const float* __restrict__ inv,
                                                 const ushort_t* __restrict__ fkH,
                                                 const ushort_t* __restrict__ fkL,
                                                 const float* __restrict__ fk2,
                                                 const float* __restrict__ disp,
                                                 float* __restrict__ out) {
    __shared__ __align__(16) ushort_t fgH[64 * 136];   // [vox][ch'] hi
    __shared__ __align__(16) ushort_t fgL[64 * 136];   // lo
    __shared__ float dspx[512], dspy[512], dspz[512];
    __shared__ float fk2s[512];
    __shared__ float mrg[64 * 4 * 5];                  // [vox][wave][{m,l,px,py,pz}]

    const int tid = threadIdx.x;
    const int gbase = blockIdx.x * 64;
    const int wave = tid >> 6, lane = tid & 63;
    const int ll = lane & 15, kq = lane >> 4;

    // ---- stage fg tile: thread = (vox = tid&63, ch-block = (tid>>6)*32), norm + split ----
    {
        int v = tid & 63;
        int c0 = (tid >> 6) * 32;
        #pragma unroll
        for (int o = 0; o < 4; ++o) {
            half8 h, l;
            #pragma unroll
            for (int j = 0; j < 8; ++j) {
                int c = c0 + o * 8 + j;
                float x = yb[(size_t)c * NG + gbase + v];
                x = (x - mu[c]) * inv[c];
                _Float16 hh = (_Float16)x;
                h[j] = hh;
                l[j] = (_Float16)(x - (float)hh);
            }
            *(half8*)&fgH[v * 136 + c0 + o * 8] = h;
            *(half8*)&fgL[v * 136 + c0 + o * 8] = l;
        }
    }
    for (int s = tid; s < 512; s += 256) {
        dspx[s] = disp[3 * s + 0];
        dspy[s] = disp[3 * s + 1];
        dspz[s] = disp[3 * s + 2];
        fk2s[s] = fk2[s];
    }
    __syncthreads();

    const int key0 = wave * 128;

    floatx4 acc[8][4];
    const floatx4 zz = {0.f, 0.f, 0.f, 0.f};
    #pragma unroll
    for (int mi = 0; mi < 8; ++mi)
        #pragma unroll
        for (int ni = 0; ni < 4; ++ni) acc[mi][ni] = zz;

    #pragma unroll
    for (int ks = 0; ks < 4; ++ks) {
        half8 Bh[4], Bl[4];
        #pragma unroll
        for (int ni = 0; ni < 4; ++ni) {
            int ad = (ni * 16 + ll) * 136 + ks * 32 + kq * 8;
            Bh[ni] = *(const half8*)&fgH[ad];
            Bl[ni] = *(const half8*)&fgL[ad];
        }
        #pragma unroll
        for (int mi = 0; mi < 8; ++mi) {
            int key = key0 + mi * 16 + ll;
            int ga = key * 128 + ks * 32 + kq * 8;
            half8 Ah = *(const half8*)&fkH[ga];
            half8 Al = *(const half8*)&fkL[ga];
            #pragma unroll
            for (int ni = 0; ni < 4; ++ni) {
                acc[mi][ni] = __builtin_amdgcn_mfma_f32_16x16x32_f16(Ah, Bh[ni], acc[mi][ni], 0, 0, 0);
                acc[mi][ni] = __builtin_amdgcn_mfma_f32_16x16x32_f16(Ah, Bl[ni], acc[mi][ni], 0, 0, 0);
                acc[mi][ni] = __builtin_amdgcn_mfma_f32_16x16x32_f16(Al, Bh[ni], acc[mi][ni], 0, 0, 0);
            }
        }
    }

    // ---- logits = 2*cross - ||fk||^2; per-vox max over this wave's 128 keys ----
    float mx[4] = {-1e30f, -1e30f, -1e30f, -1e30f};
    #pragma unroll
    for (int mi = 0; mi < 8; ++mi)
        #pragma unroll
        for (int r = 0; r < 4; ++r) {
            int key = key0 + mi * 16 + kq * 4 + r;
            float f2 = fk2s[key];
            #pragma unroll
            for (int ni = 0; ni < 4; ++ni) {
                float s = 2.f * acc[mi][ni][r] - f2;
                acc[mi][ni][r] = s;
                mx[ni] = fmaxf(mx[ni], s);
            }
        }
    #pragma unroll
    for (int ni = 0; ni < 4; ++ni) {
        mx[ni] = fmaxf(mx[ni], __shfl_xor(mx[ni], 16, 64));
        mx[ni] = fmaxf(mx[ni], __shfl_xor(mx[ni], 32, 64));
    }

    float lv[4] = {0.f, 0.f, 0.f, 0.f};
    float pxv[4] = {0.f, 0.f, 0.f, 0.f};
    float pyv[4] = {0.f, 0.f, 0.f, 0.f};
    float pzv[4] = {0.f, 0.f, 0.f, 0.f};
    #pragma unroll
    for (int mi = 0; mi < 8; ++mi)
        #pragma unroll
        for (int r = 0; r < 4; ++r) {
            int key = key0 + mi * 16 + kq * 4 + r;
            float dx = dspx[key], dy = dspy[key], dz = dspz[key];
            #pragma unroll
            for (int ni = 0; ni < 4; ++ni) {
                float p = __expf(acc[mi][ni][r] - mx[ni]);
                lv[ni] += p;
                pxv[ni] = fmaf(p, dx, pxv[ni]);
                pyv[ni] = fmaf(p, dy, pyv[ni]);
                pzv[ni] = fmaf(p, dz, pzv[ni]);
            }
        }
    #pragma unroll
    for (int ni = 0; ni < 4; ++ni) {
        lv[ni]  += __shfl_xor(lv[ni], 16, 64);  lv[ni]  += __shfl_xor(lv[ni], 32, 64);
        pxv[ni] += __shfl_xor(pxv[ni], 16, 64); pxv[ni] += __shfl_xor(pxv[ni], 32, 64);
        pyv[ni] += __shfl_xor(pyv[ni], 16, 64); pyv[ni] += __shfl_xor(pyv[ni], 32, 64);
        pzv[ni] += __shfl_xor(pzv[ni], 16, 64); pzv[ni] += __shfl_xor(pzv[ni], 32, 64);
    }

    if (kq == 0) {
        #pragma unroll
        for (int ni = 0; ni < 4; ++ni) {
            int vox = ni * 16 + ll;
            float* q = &mrg[(vox * 4 + wave) * 5];
            q[0] = mx[ni]; q[1] = lv[ni]; q[2] = pxv[ni]; q[3] = pyv[ni]; q[4] = pzv[ni];
        }
    }
    __syncthreads();

    if (tid < 64) {
        float M = -1e30f;
        #pragma unroll
        for (int w = 0; w < 4; ++w) M = fmaxf(M, mrg[(tid * 4 + w) * 5]);
        float L = 0.f, X = 0.f, Y = 0.f, Z = 0.f;
        #pragma unroll
        for (int w = 0; w < 4; ++w) {
            const float* q = &mrg[(tid * 4 + w) * 5];
            float a = __expf(q[0] - M);
            L = fmaf(q[1], a, L);
            X = fmaf(q[2], a, X);
            Y = fmaf(q[3], a, Y);
            Z = fmaf(q[4], a, Z);
        }
        float il = 1.0f / L;
        out[0 * NG + gbase + tid] = X * il;
        out[1 * NG + gbase + tid] = Y * il;
        out[2 * NG + gbase + tid] = Z * il;
    }
}

extern "C" void kernel_launch(void* const* d_in, const int* in_sizes, int n_in,
                              void* d_out, int out_size, void* d_ws, size_t ws_size,
                              hipStream_t stream) {
    const float* kpts  = (const float*)d_in[0];   // (1,512,3)
    const float* disp  = (const float*)d_in[1];   // (1,512,3)
    const float* feats = (const float*)d_in[2];   // (1,125,48,48,48)
    const float* W0    = (const float*)d_in[3];   // (128,128,3,3,3)
    const float* b0    = (const float*)d_in[4];   // (128,)

    float* ws = (float*)d_ws;
    float*    yb   = ws;                                   // 128*110592 floats
    ushort_t* Wp   = (ushort_t*)(yb + (size_t)NCH * NG);   // 884736 u16 (= 442368 f32 slots)
    float*    gsum = yb + (size_t)NCH * NG + 442368;       // 128
    float*    gsq  = gsum + 128;                           // 128
    float*    mu   = gsq + 128;                            // 128
    float*    ivr  = mu + 128;                             // 128
    float*    fk2  = ivr + 128;                            // 512
    ushort_t* fkH  = (ushort_t*)(fk2 + 512);               // 65536 u16
    ushort_t* fkL  = fkH + 65536;                          // 65536 u16

    k_prep_w<<<3456, 256, 0, stream>>>(W0, Wp);
    hipMemsetAsync(gsum, 0, 256 * sizeof(float), stream);
    k_conv<<<864, 256, 0, stream>>>(feats, Wp, b0, yb, gsum, gsq);
    k_finalize<<<1, 128, 0, stream>>>(gsum, gsq, mu, ivr);
    k_sample<<<NKP, 128, 0, stream>>>(kpts, yb, mu, ivr, fkH, fkL, fk2);
    k_attn<<<1728, 256, 0, stream>>>(yb, mu, ivr, fkH, fkL, fk2, disp, (float*)d_out);
}